// Round 7
// baseline (2078.751 us; speedup 1.0000x reference)
//
#include <hip/hip_runtime.h>

#define TT   512
#define IDIM 64
#define HDIM 256

typedef short  short8  __attribute__((ext_vector_type(8)));
typedef short  short4v __attribute__((ext_vector_type(4)));
typedef float  f32x4   __attribute__((ext_vector_type(4)));
typedef unsigned long long u64;

__device__ __forceinline__ short f2bf(float f) {
    unsigned u = __float_as_uint(f);
    u = u + 0x7FFFu + ((u >> 16) & 1u);   // round-to-nearest-even
    return (short)(u >> 16);
}
__device__ __forceinline__ float bf2f(short h) {
    return __uint_as_float(((unsigned)(unsigned short)h) << 16);
}
__device__ __forceinline__ float sigm(float x)  { return 1.0f / (1.0f + __expf(-x)); }
__device__ __forceinline__ float tanh_(float x) { return 2.0f / (1.0f + __expf(-2.0f * x)) - 1.0f; }

// 128 persistent workgroups = 16 batch-groups (grp, 16 rows) x 8 hidden-chunks
// (32 units each), 512 threads/block (8 waves: waves 0-3 layer0, 4-7 layer1 —
// the two layers' MFMA phases now run CONCURRENTLY on different waves).
// Exchange protocol = round-5/6 PROVEN, unchanged: every published 8B word =
// [3 bf16 units | seq16], seq = s+1; agent-scope swap publish; readers poll the
// tags (the tag certifies its own 3 units — no flags, no acks, no ordering
// requirements anywhere); 2 regions (parity s&1); recycle-safe (publish s+2
// only after s+1 gather); poll budget => hang-proof.
// Geometry change rationale: r0/r5/r6 tie at ~3.5us/step across protocol
// variants => cost is MALL fan-in traffic + 16-publisher convoy + serial
// compute, not protocol round trips. 8 blocks/grp halves fan-in and convoy;
// own-chunk h short-circuits via LDS; A0/A1 row strides re-padded (dword
// stride ≡ 12 mod 32) to kill the 8-way ds_read_b128 bank conflicts.
// Per row per buf: 8 chunks x 11 words (10x3 + 1x2 units = 32 units, 88B).
__global__ __launch_bounds__(512, 1) void lstm_fused(
    const float* __restrict__ x,
    const float* __restrict__ Wih0, const float* __restrict__ Whh0,
    const float* __restrict__ bih0, const float* __restrict__ bhh0,
    const float* __restrict__ Wih1, const float* __restrict__ Whh1,
    const float* __restrict__ bih1, const float* __restrict__ bhh1,
    const float* __restrict__ Wfc,  const float* __restrict__ bfc,
    float* __restrict__ out, char* __restrict__ ws)
{
    u64* h0buf = (u64*)ws;                    // [2][16][16][88] seq-tagged words
    u64* h1buf = h0buf + 2 * 16 * 16 * 88;    // [2][16][16][88]
    // total = 704 KiB (< proven 1 MiB ws capacity)

    const int blk   = blockIdx.x;
    const int grp   = ((blk & 7) << 1) | ((blk >> 3) & 1); // batch-group 0..15
    const int chunk = blk >> 4;                            // hidden-chunk 0..7
    const int tid   = threadIdx.x;       // 0..511
    const int lane  = tid & 63;
    const int wave  = tid >> 6;          // 0..7
    const int lay   = wave >> 2;         // 0: layer0 waves, 1: layer1 waves
    const int gate  = wave & 3;          // i,f,g,o
    const int quad  = lane >> 4;
    const int nn    = lane & 15;

    // A row strides: 344/536 shorts -> dword stride 172/268 ≡ 12 (mod 32)
    // -> ds_read_b128 feed conflicts reduced to 2-way (free).
    __shared__ short A0[16][344];    // [m][ x(64) | h0(256) | pad ]
    __shared__ short A1[16][536];    // [m][ h0(256) | h1(256) | pad ]
    __shared__ float gbuf[2][4][16][34];
    __shared__ float red[16][32];
    __shared__ short hls[2][16][32]; // h staging (32 units per chunk)

    // zero A buffers (h0[-1] = 0, h1[-1] = 0 for the s==1 layer1 step)
    for (int i = tid; i < 16 * 344; i += 512) (&A0[0][0])[i] = 0;
    for (int i = tid; i < 16 * 536; i += 512) (&A1[0][0])[i] = 0;

    // ---- static weight fragments (each wave: its layer, its gate, 2 N-tiles)
    short8 wf[2][16];   // [tile][kb]; layer0 uses kb<10, layer1 kb<16
    float  bias[2];
    if (lay == 0) {
#pragma unroll
        for (int n = 0; n < 2; ++n) {
            const int row = gate * HDIM + chunk * 32 + n * 16 + nn;
#pragma unroll
            for (int kb = 0; kb < 10; ++kb)
#pragma unroll
                for (int j = 0; j < 8; ++j) {
                    int k = kb * 32 + quad * 8 + j;
                    float v = (k < 64) ? Wih0[row * IDIM + k]
                                       : Whh0[row * HDIM + (k - 64)];
                    wf[n][kb][j] = f2bf(v);
                }
            bias[n] = bih0[row] + bhh0[row];
        }
    } else {
#pragma unroll
        for (int n = 0; n < 2; ++n) {
            const int row = gate * HDIM + chunk * 32 + n * 16 + nn;
#pragma unroll
            for (int kb = 0; kb < 16; ++kb)
#pragma unroll
                for (int j = 0; j < 8; ++j) {
                    int k = kb * 32 + quad * 8 + j;
                    float v = (k < 256) ? Wih1[row * HDIM + k]
                                        : Whh1[row * HDIM + (k - 256)];
                    wf[n][kb][j] = f2bf(v);
                }
            bias[n] = bih1[row] + bhh1[row];
        }
    }

    const int em = tid >> 5;   // batch row (0..15)
    const int eu = tid & 31;   // hidden unit within chunk (0..31)
    float c0 = 0.0f, c1 = 0.0f;

    auto load_x = [&](int t) {   // only eu<16 threads call (16 lanes x 4 floats)
        const float4 v = *(const float4*)&x[((size_t)(grp * 16 + em) * TT + t) * IDIM + eu * 4];
        short4v sv;
        sv[0] = f2bf(v.x); sv[1] = f2bf(v.y); sv[2] = f2bf(v.z); sv[3] = f2bf(v.w);
        *(short4v*)&A0[em][eu * 4] = sv;
    };

    // poll geometry: 16 threads per (buf,row) pair cover 7 remote chunks x 11 words
    const int pp   = tid >> 4;       // 0..31
    const int pj   = tid & 15;
    const int pbuf = pp >> 4;        // 0 = h0, 1 = h1
    const int prow = pp & 15;

    __syncthreads();
    if (eu < 16) load_x(0);
    __syncthreads();

    // super-step s: layer0 computes h0[s] (s<T); layer1 computes h1[s-1] (s>=1)
    for (int s = 0; s <= TT; ++s) {
        // ---- MFMA phase: layer waves in parallel; shared A-reads feed both tiles
        if (lay == 0) {
            if (s < TT) {
                f32x4 a00 = {0,0,0,0}, a01 = {0,0,0,0}, a10 = {0,0,0,0}, a11 = {0,0,0,0};
#pragma unroll
                for (int kb = 0; kb < 10; kb += 2) {
                    short8 av0 = *(const short8*)&A0[nn][kb * 32 + quad * 8];
                    short8 av1 = *(const short8*)&A0[nn][(kb + 1) * 32 + quad * 8];
                    a00 = __builtin_amdgcn_mfma_f32_16x16x32_bf16(av0, wf[0][kb],     a00, 0, 0, 0);
                    a10 = __builtin_amdgcn_mfma_f32_16x16x32_bf16(av0, wf[1][kb],     a10, 0, 0, 0);
                    a01 = __builtin_amdgcn_mfma_f32_16x16x32_bf16(av1, wf[0][kb + 1], a01, 0, 0, 0);
                    a11 = __builtin_amdgcn_mfma_f32_16x16x32_bf16(av1, wf[1][kb + 1], a11, 0, 0, 0);
                }
                const f32x4 t0 = a00 + a01, t1 = a10 + a11;
#pragma unroll
                for (int r = 0; r < 4; ++r) {
                    gbuf[0][gate][quad * 4 + r][nn]      = t0[r] + bias[0];
                    gbuf[0][gate][quad * 4 + r][16 + nn] = t1[r] + bias[1];
                }
            }
        } else {
            if (s >= 1) {
                f32x4 a00 = {0,0,0,0}, a01 = {0,0,0,0}, a10 = {0,0,0,0}, a11 = {0,0,0,0};
#pragma unroll
                for (int kb = 0; kb < 16; kb += 2) {
                    short8 av0 = *(const short8*)&A1[nn][kb * 32 + quad * 8];
                    short8 av1 = *(const short8*)&A1[nn][(kb + 1) * 32 + quad * 8];
                    a00 = __builtin_amdgcn_mfma_f32_16x16x32_bf16(av0, wf[0][kb],     a00, 0, 0, 0);
                    a10 = __builtin_amdgcn_mfma_f32_16x16x32_bf16(av0, wf[1][kb],     a10, 0, 0, 0);
                    a01 = __builtin_amdgcn_mfma_f32_16x16x32_bf16(av1, wf[0][kb + 1], a01, 0, 0, 0);
                    a11 = __builtin_amdgcn_mfma_f32_16x16x32_bf16(av1, wf[1][kb + 1], a11, 0, 0, 0);
                }
                const f32x4 t0 = a00 + a01, t1 = a10 + a11;
#pragma unroll
                for (int r = 0; r < 4; ++r) {
                    gbuf[1][gate][quad * 4 + r][nn]      = t0[r] + bias[0];
                    gbuf[1][gate][quad * 4 + r][16 + nn] = t1[r] + bias[1];
                }
            }
        }
        __syncthreads();

        // ---- elementwise LSTM cell updates -> stage h in LDS (bf16)
        if (s < TT) {
            float gi = sigm (gbuf[0][0][em][eu]);
            float gf = sigm (gbuf[0][1][em][eu]);
            float gg = tanh_(gbuf[0][2][em][eu]);
            float go = sigm (gbuf[0][3][em][eu]);
            c0 = gf * c0 + gi * gg;
            hls[0][em][eu] = f2bf(go * tanh_(c0));
        }
        if (s >= 1) {
            float gi = sigm (gbuf[1][0][em][eu]);
            float gf = sigm (gbuf[1][1][em][eu]);
            float gg = tanh_(gbuf[1][2][em][eu]);
            float go = sigm (gbuf[1][3][em][eu]);
            c1 = gf * c1 + gi * gg;
            hls[1][em][eu] = f2bf(go * tanh_(c1));
        } else {
            hls[1][em][eu] = 0;
        }
        __syncthreads();   // hls complete

        // ---- own chunk short-circuits via LDS (never round-trips the fabric)
        {
            const short h0v = hls[0][em][eu], h1v = hls[1][em][eu];
            A0[em][64 + chunk * 32 + eu]  = h0v;
            A1[em][chunk * 32 + eu]       = h0v;
            A1[em][256 + chunk * 32 + eu] = h1v;
        }

        // ---- publish own chunk, seq-tagged, agent swap (r6 transport):
        // 352 words = 2 bufs x 16 rows x 11 words, one thread each.
        if (tid < 352) {
            const int b  = tid / 176;
            const int r2 = (tid % 176) / 11;
            const int w  = tid % 11;
            const int j0 = 3 * w;
            const int kc = (w == 10) ? 2 : 3;
            u64 v = (u64)(unsigned)(s + 1) << 48;
#pragma unroll
            for (int k = 0; k < 3; ++k)
                if (k < kc) v |= (u64)(unsigned short)hls[b][r2][j0 + k] << (16 * k);
            const size_t gi_ = (((size_t)(s & 1) * 16 + grp) * 16 + r2) * 88 + chunk * 11 + w;
            u64* dst = (b == 0 ? h0buf : h1buf) + gi_;
            (void)__hip_atomic_exchange(dst, v, __ATOMIC_RELAXED, __HIP_MEMORY_SCOPE_AGENT);
        }

        if (s + 1 < TT && eu < 16) load_x(s + 1);   // overlap x prefetch with poll

        // ---- seq-poll + gather of the 7 remote chunks (poll result IS the data)
        {
            const bool need = (pbuf == 0) ? (s < TT) : (s >= 1);
            const int  nw   = need ? ((pj < 13) ? 5 : 4) : 0;
            const unsigned sq = (unsigned)(s + 1);
            u64* const buf = pbuf ? h1buf : h0buf;
            const size_t rowbase = (((size_t)(s & 1) * 16 + grp) * 16 + prow) * 88;
            int cc[5], wii[5];
            const u64* ptr[5];
#pragma unroll
            for (int m = 0; m < 5; ++m) {
                const int widx = (pj + 16 * m < 77) ? (pj + 16 * m) : 0;
                const int c2 = widx / 11;
                const int wi = widx - 11 * c2;
                const int c  = c2 + (c2 >= chunk);
                cc[m] = c; wii[m] = wi;
                ptr[m] = buf + rowbase + c * 11 + wi;
            }
            u64  W[5]   = {0, 0, 0, 0, 0};
            bool got[5] = {false, false, false, false, false};
            int budget = 1 << 17;   // hang-proofing: exhaust -> finite absmax fail
            bool all = (nw == 0);
            while (!all && budget-- > 0) {
                all = true;
#pragma unroll
                for (int m = 0; m < 5; ++m)
                    if (m < nw && !got[m]) {
                        const u64 v = __hip_atomic_load(ptr[m],
                                          __ATOMIC_RELAXED, __HIP_MEMORY_SCOPE_AGENT);
                        if ((unsigned)(v >> 48) == sq) { W[m] = v; got[m] = true; }
                        else all = false;
                    }
            }
            asm volatile("s_waitcnt vmcnt(0)" ::: "memory");   // drain publishes/polls
#pragma unroll
            for (int m = 0; m < 5; ++m)
                if (m < nw) {
                    const int u0 = cc[m] * 32 + wii[m] * 3;
                    const int kc = (wii[m] == 10) ? 2 : 3;
#pragma unroll
                    for (int k = 0; k < 3; ++k)
                        if (k < kc) {
                            const short h = (short)(unsigned short)(W[m] >> (16 * k));
                            if (pbuf == 0) {
                                A0[prow][64 + u0 + k] = h;
                                A1[prow][u0 + k]      = h;
                            } else {
                                A1[prow][256 + u0 + k] = h;
                            }
                        }
                }
        }
        __syncthreads();
    }

    // FC epilogue: A1[:,256..511] holds h1[T-1] (bf16)
    {
        float part = 0.f;
#pragma unroll
        for (int kk = 0; kk < 8; ++kk) {
            const int k = eu * 8 + kk;
            part += bf2f(A1[em][256 + k]) * Wfc[k];
        }
        red[em][eu] = part;
    }
    __syncthreads();
    if (chunk == 0 && tid < 16) {
        float sum = bfc[0];
#pragma unroll
        for (int c = 0; c < 32; ++c) sum += red[tid][c];
        out[grp * 16 + tid] = sum;
    }
}

extern "C" void kernel_launch(void* const* d_in, const int* in_sizes, int n_in,
                              void* d_out, int out_size, void* d_ws, size_t ws_size,
                              hipStream_t stream) {
    (void)in_sizes; (void)n_in; (void)out_size; (void)ws_size;
    const float* x    = (const float*)d_in[0];
    const float* Wih0 = (const float*)d_in[1];
    const float* Whh0 = (const float*)d_in[2];
    const float* bih0 = (const float*)d_in[3];
    const float* bhh0 = (const float*)d_in[4];
    const float* Wih1 = (const float*)d_in[5];
    const float* Whh1 = (const float*)d_in[6];
    const float* bih1 = (const float*)d_in[7];
    const float* bhh1 = (const float*)d_in[8];
    const float* Wfc  = (const float*)d_in[9];
    const float* bfc  = (const float*)d_in[10];

    lstm_fused<<<128, 512, 0, stream>>>(x, Wih0, Whh0, bih0, bhh0,
                                        Wih1, Whh1, bih1, bhh1, Wfc, bfc,
                                        (float*)d_out, (char*)d_ws);
}